// Round 1
// baseline (622.565 us; speedup 1.0000x reference)
//
#include <hip/hip_runtime.h>
#include <math.h>

#define T_OBS 256
#define NY 128
#define EPS 132           // LDS row stride for ep (floats): breaks bank aliasing, keeps 16B align
#define NITER 150

// ---------------- kernel 1: Y_hat = X @ W^T + b ; ep = Y - Y_hat ----------------
__global__ __launch_bounds__(128)
void pred_kernel(const float* __restrict__ X, const float* __restrict__ Y,
                 const float* __restrict__ W, const float* __restrict__ b,
                 float* __restrict__ yhat, float* __restrict__ ep) {
    __shared__ float xrow[64];
    const int t = blockIdx.x;
    const int j = threadIdx.x;
    if (j < 64) xrow[j] = X[t * 64 + j];
    __syncthreads();
    const float* wr = W + j * 64;
    float acc = 0.f;
#pragma unroll
    for (int x = 0; x < 64; ++x) acc = fmaf(xrow[x], wr[x], acc);
    const float yh = acc + b[j];
    yhat[t * NY + j] = yh;
    ep[t * NY + j] = Y[t * NY + j] - yh;
}

// ---------------- kernel 2: one DRO solve per block ----------------
__global__ __launch_bounds__(256, 1)
void dro_kernel(const float* __restrict__ ep_g, const float* __restrict__ yhat_g,
                float* __restrict__ z_out,
                const float* __restrict__ d_delta, const float* __restrict__ d_gamma) {
    __shared__ float ep[T_OBS * EPS];   // 132 KB
    __shared__ float z_s[2][NY];
    __shared__ float y_s[NY];
    __shared__ float w_s[T_OBS];
    __shared__ float gzp[4][NY];
    __shared__ float red[8];

    const int tid  = threadIdx.x;
    const int lane = tid & 63;
    const int wid  = tid >> 6;
    const int blk  = blockIdx.x;

    // stage ep (coalesced float4 global reads -> padded LDS rows)
    const float4* epg4 = (const float4*)ep_g;
#pragma unroll
    for (int it = 0; it < 32; ++it) {
        const int fi  = it * 256 + tid;     // float4 index 0..8191
        const float4 v = epg4[fi];
        const int e   = fi << 2;
        const int row = e >> 7;
        const int col = e & 127;
        *(float4*)&ep[row * EPS + col] = v;
    }
    if (tid < NY) {
        y_s[tid]    = yhat_g[blk * NY + tid];
        z_s[0][tid] = 1.0f / 128.0f;
    }
    const float delta = d_delta[0];
    const float gamma = d_gamma[0];
    float c = 0.f, eta = 0.f, lam = 0.1f;
    int cur = 0;
    __syncthreads();

    for (int k = 0; k < NITER; ++k) {
        const float lr = 0.05f / sqrtf(1.0f + (float)k);

        // ---- phase A: r_t = ep[t,:].z - c  (thread t = tid) ----
        const float*  row = ep + tid * EPS;
        const float4* z4p = (const float4*)z_s[cur];
        float4 a4 = make_float4(0.f, 0.f, 0.f, 0.f);
#pragma unroll
        for (int q = 0; q < 32; ++q) {
            const float4 e4 = *(const float4*)(row + (q << 2));
            const float4 z4 = z4p[q];
            a4.x = fmaf(e4.x, z4.x, a4.x);
            a4.y = fmaf(e4.y, z4.y, a4.y);
            a4.z = fmaf(e4.z, z4.z, a4.z);
            a4.w = fmaf(e4.w, z4.w, a4.w);
        }
        const float r  = (a4.x + a4.y) + (a4.z + a4.w) - c;
        const float q2 = r * r - eta;
        const float aa = -lam;
        // JAX balanced-eq subgradient of maximum: 1 / 0.5 (tie) / 0
        const float st = (q2 > aa) ? 1.0f : ((q2 == aa) ? 0.5f : 0.0f);
        const float wv = st * r;
        w_s[tid] = wv;
        float s1 = st, s2 = wv;
#pragma unroll
        for (int off = 32; off; off >>= 1) {
            s1 += __shfl_xor(s1, off, 64);
            s2 += __shfl_xor(s2, off, 64);
        }
        if (lane == 0) { red[wid * 2] = s1; red[wid * 2 + 1] = s2; }
        __syncthreads();   // A

        const float S1 = red[0] + red[2] + red[4] + red[6];
        const float S2 = red[1] + red[3] + red[5] + red[7];
        const float gc   = -(2.0f / 256.0f) * S2;
        const float geta = 1.0f - S1 * (1.0f / 256.0f);
        const float glam = delta - 1.0f + S1 * (1.0f / 256.0f);
        c   -= lr * gc;
        eta -= lr * geta;
        lam  = fmaxf(lam - lr * glam, 0.0f);

        // ---- phase B: per-wave partial gz over 64 rows, cols (2*lane, 2*lane+1) ----
        const int j0 = lane << 1;
        const int tbase = wid << 6;
        float p0 = 0.f, p1 = 0.f;
#pragma unroll 16
        for (int tt = 0; tt < 64; ++tt) {
            const int t = tbase + tt;
            const float wb = w_s[t];                                  // broadcast
            const float2 e2 = *(const float2*)(ep + t * EPS + j0);    // conflict-free
            p0 = fmaf(wb, e2.x, p0);
            p1 = fmaf(wb, e2.y, p1);
        }
        *(float2*)&gzp[wid][j0] = make_float2(p0, p1);
        __syncthreads();   // B

        // ---- update z + exact simplex projection (wave 0, shuffle-only Michelot) ----
        if (wid == 0) {
            const int j1 = j0 + 1;
            const float g0 = gzp[0][j0] + gzp[1][j0] + gzp[2][j0] + gzp[3][j0];
            const float g1 = gzp[0][j1] + gzp[1][j1] + gzp[2][j1] + gzp[3][j1];
            const float gz0 = (2.0f / 256.0f) * g0 - gamma * y_s[j0];
            const float gz1 = (2.0f / 256.0f) * g1 - gamma * y_s[j1];
            const float v0 = z_s[cur][j0] - lr * gz0;
            const float v1 = z_s[cur][j1] - lr * gz1;
            // Michelot active-set: exact same fixed point as the sort-based formula
            float act0 = 1.f, act1 = 1.f;
            float prev = 1e30f;
            float theta = 0.f;
            for (int m = 0; m < 140; ++m) {
                float s  = act0 * v0 + act1 * v1;
                float cc = act0 + act1;
#pragma unroll
                for (int off = 32; off; off >>= 1) {
                    s  += __shfl_xor(s, off, 64);
                    cc += __shfl_xor(cc, off, 64);
                }
                theta = (s - 1.0f) / cc;
                if (cc == prev) break;   // active set stable -> converged (wave-uniform)
                prev = cc;
                act0 = (v0 > theta) ? act0 : 0.f;
                act1 = (v1 > theta) ? act1 : 0.f;
            }
            z_s[cur ^ 1][j0] = fmaxf(v0 - theta, 0.f);
            z_s[cur ^ 1][j1] = fmaxf(v1 - theta, 0.f);
        }
        __syncthreads();   // D
        cur ^= 1;
    }

    if (tid < NY) z_out[blk * NY + tid] = z_s[cur][tid];
}

extern "C" void kernel_launch(void* const* d_in, const int* in_sizes, int n_in,
                              void* d_out, int out_size, void* d_ws, size_t ws_size,
                              hipStream_t stream) {
    const float* X       = (const float*)d_in[0];   // 256*64
    const float* Y       = (const float*)d_in[1];   // 256*128
    const float* W       = (const float*)d_in[2];   // 128*64
    const float* b       = (const float*)d_in[3];   // 128
    const float* d_delta = (const float*)d_in[4];   // 1
    const float* d_gamma = (const float*)d_in[5];   // 1

    float* z_out    = (float*)d_out;                // Z_star: 256*128
    float* yhat_out = z_out + T_OBS * NY;           // Y_hat:  256*128
    float* ep_ws    = (float*)d_ws;                 // 256*128 scratch

    pred_kernel<<<T_OBS, 128, 0, stream>>>(X, Y, W, b, yhat_out, ep_ws);
    dro_kernel<<<T_OBS, 256, 0, stream>>>(ep_ws, yhat_out, z_out, d_delta, d_gamma);
}

// Round 2
// 417.014 us; speedup vs baseline: 1.4929x; 1.4929x over previous
//
#include <hip/hip_runtime.h>
#include <math.h>

#define T_OBS 256
#define NY 128
#define NITER 150

// ---- gfx9/CDNA DPP wave64 reduction: row_shr 1,2,4,8 + bcast15 + bcast31 ----
#define DPP_ROW_SHR1 0x111
#define DPP_ROW_SHR2 0x112
#define DPP_ROW_SHR4 0x114
#define DPP_ROW_SHR8 0x118
#define DPP_BCAST15  0x142
#define DPP_BCAST31  0x143

#define DPP_ADD_F32(x, ctrl) \
    (x) += __int_as_float(__builtin_amdgcn_update_dpp(0, __float_as_int(x), (ctrl), 0xf, 0xf, true))

// Interleaved dual wave-sum; returns uniform (SGPR) totals in a,b.
__device__ __forceinline__ void wave_sum2(float& a, float& b) {
    DPP_ADD_F32(a, DPP_ROW_SHR1); DPP_ADD_F32(b, DPP_ROW_SHR1);
    DPP_ADD_F32(a, DPP_ROW_SHR2); DPP_ADD_F32(b, DPP_ROW_SHR2);
    DPP_ADD_F32(a, DPP_ROW_SHR4); DPP_ADD_F32(b, DPP_ROW_SHR4);
    DPP_ADD_F32(a, DPP_ROW_SHR8); DPP_ADD_F32(b, DPP_ROW_SHR8);
    DPP_ADD_F32(a, DPP_BCAST15);  DPP_ADD_F32(b, DPP_BCAST15);
    DPP_ADD_F32(a, DPP_BCAST31);  DPP_ADD_F32(b, DPP_BCAST31);
    a = __int_as_float(__builtin_amdgcn_readlane(__float_as_int(a), 63));
    b = __int_as_float(__builtin_amdgcn_readlane(__float_as_int(b), 63));
}

// ---------------- kernel 1: Y_hat = X @ W^T + b ; ep = Y - Y_hat ----------------
__global__ __launch_bounds__(128)
void pred_kernel(const float* __restrict__ X, const float* __restrict__ Y,
                 const float* __restrict__ W, const float* __restrict__ b,
                 float* __restrict__ yhat, float* __restrict__ ep) {
    __shared__ float xrow[64];
    const int t = blockIdx.x;
    const int j = threadIdx.x;
    if (j < 64) xrow[j] = X[t * 64 + j];
    __syncthreads();
    const float* wr = W + j * 64;
    float acc = 0.f;
#pragma unroll
    for (int x = 0; x < 64; ++x) acc = fmaf(xrow[x], wr[x], acc);
    const float yh = acc + b[j];
    yhat[t * NY + j] = yh;
    ep[t * NY + j] = Y[t * NY + j] - yh;
}

// ---------------- kernel 2: one DRO solve per block, ep in registers ----------------
__global__ __launch_bounds__(256, 1)
void dro_kernel(const float* __restrict__ ep_g, const float* __restrict__ yhat_g,
                float* __restrict__ z_out,
                const float* __restrict__ d_delta, const float* __restrict__ d_gamma) {
    __shared__ float z_s[2][NY];
    __shared__ float y_s[NY];
    __shared__ float w_s[T_OBS];
    __shared__ float gzp[4][NY];
    __shared__ float red[8];

    const int tid  = threadIdx.x;
    const int lane = tid & 63;
    const int wid  = tid >> 6;
    const int blk  = blockIdx.x;

    // --- row layout: thread tid holds ep[tid][0..127] (32 float4 = 128 VGPRs) ---
    float4 rA[32];
    {
        const float4* eg4 = (const float4*)ep_g + tid * 32;
#pragma unroll
        for (int q = 0; q < 32; ++q) rA[q] = eg4[q];
    }

    // --- col layout: thread (wid,lane) holds ep[tbase+tt][j0..j0+1], tt=0..63 ---
    const int j0    = lane << 1;
    const int tbase = wid << 6;
    float2 rB[64];
#pragma unroll
    for (int tt = 0; tt < 64; ++tt)
        rB[tt] = *(const float2*)(ep_g + (tbase + tt) * NY + j0);

    if (tid < NY) {
        y_s[tid]    = yhat_g[blk * NY + tid];
        z_s[0][tid] = 1.0f / 128.0f;
    }
    const float delta = d_delta[0];
    const float gamma = d_gamma[0];
    float c = 0.f, eta = 0.f, lam = 0.1f;
    int cur = 0;
    __syncthreads();

    for (int k = 0; k < NITER; ++k) {
        const float lr = 0.05f / sqrtf(1.0f + (float)k);

        // ---- phase A: r_t = ep[t,:].z - c  (thread t = tid, ep from regs, z broadcast) ----
        const float4* z4p = (const float4*)z_s[cur];
        float4 a4 = make_float4(0.f, 0.f, 0.f, 0.f);
#pragma unroll
        for (int q = 0; q < 32; ++q) {
            const float4 e4 = rA[q];
            const float4 z4 = z4p[q];
            a4.x = fmaf(e4.x, z4.x, a4.x);
            a4.y = fmaf(e4.y, z4.y, a4.y);
            a4.z = fmaf(e4.z, z4.z, a4.z);
            a4.w = fmaf(e4.w, z4.w, a4.w);
        }
        const float r  = (a4.x + a4.y) + (a4.z + a4.w) - c;
        const float q2 = r * r - eta;
        const float aa = -lam;
        // JAX balanced-eq subgradient of maximum: 1 / 0.5 (tie) / 0
        const float st = (q2 > aa) ? 1.0f : ((q2 == aa) ? 0.5f : 0.0f);
        const float wv = st * r;
        w_s[tid] = wv;
        float s1 = st, s2 = wv;
        wave_sum2(s1, s2);
        if (lane == 0) { red[wid * 2] = s1; red[wid * 2 + 1] = s2; }
        __syncthreads();   // A: w_s + red visible

        const float S1 = red[0] + red[2] + red[4] + red[6];
        const float S2 = red[1] + red[3] + red[5] + red[7];
        const float gc   = -(2.0f / 256.0f) * S2;
        const float geta = 1.0f - S1 * (1.0f / 256.0f);
        const float glam = delta - 1.0f + S1 * (1.0f / 256.0f);
        c   -= lr * gc;
        eta -= lr * geta;
        lam  = fmaxf(lam - lr * glam, 0.0f);

        // ---- phase B: per-wave partial gz over 64 rows (ep from regs, w broadcast b128) ----
        float p0 = 0.f, p1 = 0.f;
#pragma unroll
        for (int g = 0; g < 16; ++g) {
            const float4 w4 = *(const float4*)&w_s[tbase + (g << 2)];
            const float2 e0 = rB[(g << 2) + 0];
            const float2 e1 = rB[(g << 2) + 1];
            const float2 e2 = rB[(g << 2) + 2];
            const float2 e3 = rB[(g << 2) + 3];
            p0 = fmaf(w4.x, e0.x, p0); p1 = fmaf(w4.x, e0.y, p1);
            p0 = fmaf(w4.y, e1.x, p0); p1 = fmaf(w4.y, e1.y, p1);
            p0 = fmaf(w4.z, e2.x, p0); p1 = fmaf(w4.z, e2.y, p1);
            p0 = fmaf(w4.w, e3.x, p0); p1 = fmaf(w4.w, e3.y, p1);
        }
        *(float2*)&gzp[wid][j0] = make_float2(p0, p1);
        __syncthreads();   // B: gzp visible

        // ---- update z + exact simplex projection (wave 0, DPP Michelot) ----
        if (wid == 0) {
            const int j1 = j0 + 1;
            const float g0 = gzp[0][j0] + gzp[1][j0] + gzp[2][j0] + gzp[3][j0];
            const float g1 = gzp[0][j1] + gzp[1][j1] + gzp[2][j1] + gzp[3][j1];
            const float gz0 = (2.0f / 256.0f) * g0 - gamma * y_s[j0];
            const float gz1 = (2.0f / 256.0f) * g1 - gamma * y_s[j1];
            const float v0 = z_s[cur][j0] - lr * gz0;
            const float v1 = z_s[cur][j1] - lr * gz1;
            float act0 = 1.f, act1 = 1.f;
            float prev = 1e30f;
            float theta = 0.f;
            for (int m = 0; m < 64; ++m) {
                float s  = act0 * v0 + act1 * v1;
                float cc = act0 + act1;
                wave_sum2(s, cc);          // uniform totals
                theta = (s - 1.0f) / cc;
                if (cc == prev) break;     // active set stable (uniform branch)
                prev = cc;
                act0 = (v0 > theta) ? act0 : 0.f;
                act1 = (v1 > theta) ? act1 : 0.f;
            }
            z_s[cur ^ 1][j0] = fmaxf(v0 - theta, 0.f);
            z_s[cur ^ 1][j1] = fmaxf(v1 - theta, 0.f);
        }
        __syncthreads();   // C: z visible
        cur ^= 1;
    }

    if (tid < NY) z_out[blk * NY + tid] = z_s[cur][tid];
}

extern "C" void kernel_launch(void* const* d_in, const int* in_sizes, int n_in,
                              void* d_out, int out_size, void* d_ws, size_t ws_size,
                              hipStream_t stream) {
    const float* X       = (const float*)d_in[0];   // 256*64
    const float* Y       = (const float*)d_in[1];   // 256*128
    const float* W       = (const float*)d_in[2];   // 128*64
    const float* b       = (const float*)d_in[3];   // 128
    const float* d_delta = (const float*)d_in[4];   // 1
    const float* d_gamma = (const float*)d_in[5];   // 1

    float* z_out    = (float*)d_out;                // Z_star: 256*128
    float* yhat_out = z_out + T_OBS * NY;           // Y_hat:  256*128
    float* ep_ws    = (float*)d_ws;                 // 256*128 scratch

    pred_kernel<<<T_OBS, 128, 0, stream>>>(X, Y, W, b, yhat_out, ep_ws);
    dro_kernel<<<T_OBS, 256, 0, stream>>>(ep_ws, yhat_out, z_out, d_delta, d_gamma);
}

// Round 3
// 371.512 us; speedup vs baseline: 1.6758x; 1.1225x over previous
//
#include <hip/hip_runtime.h>
#include <math.h>

#define T_OBS 256
#define NY 128
#define NITER 150

// ---- gfx9/CDNA DPP wave64 reduction: row_shr 1,2,4,8 + bcast15 + bcast31 ----
#define DPP_ROW_SHR1 0x111
#define DPP_ROW_SHR2 0x112
#define DPP_ROW_SHR4 0x114
#define DPP_ROW_SHR8 0x118
#define DPP_BCAST15  0x142
#define DPP_BCAST31  0x143

#define DPP_ADD_F32(x, ctrl) \
    (x) += __int_as_float(__builtin_amdgcn_update_dpp(0, __float_as_int(x), (ctrl), 0xf, 0xf, true))

// Interleaved dual wave-sum; returns uniform (SGPR-broadcast) totals in a,b.
__device__ __forceinline__ void wave_sum2(float& a, float& b) {
    DPP_ADD_F32(a, DPP_ROW_SHR1); DPP_ADD_F32(b, DPP_ROW_SHR1);
    DPP_ADD_F32(a, DPP_ROW_SHR2); DPP_ADD_F32(b, DPP_ROW_SHR2);
    DPP_ADD_F32(a, DPP_ROW_SHR4); DPP_ADD_F32(b, DPP_ROW_SHR4);
    DPP_ADD_F32(a, DPP_ROW_SHR8); DPP_ADD_F32(b, DPP_ROW_SHR8);
    DPP_ADD_F32(a, DPP_BCAST15);  DPP_ADD_F32(b, DPP_BCAST15);
    DPP_ADD_F32(a, DPP_BCAST31);  DPP_ADD_F32(b, DPP_BCAST31);
    a = __int_as_float(__builtin_amdgcn_readlane(__float_as_int(a), 63));
    b = __int_as_float(__builtin_amdgcn_readlane(__float_as_int(b), 63));
}

// ---------------- kernel 1: Y_hat = X @ W^T + b ; ep = Y - Y_hat ----------------
__global__ __launch_bounds__(128)
void pred_kernel(const float* __restrict__ X, const float* __restrict__ Y,
                 const float* __restrict__ W, const float* __restrict__ b,
                 float* __restrict__ yhat, float* __restrict__ ep) {
    __shared__ float xrow[64];
    const int t = blockIdx.x;
    const int j = threadIdx.x;
    if (j < 64) xrow[j] = X[t * 64 + j];
    __syncthreads();
    const float* wr = W + j * 64;
    float acc = 0.f;
#pragma unroll
    for (int x = 0; x < 64; ++x) acc = fmaf(xrow[x], wr[x], acc);
    const float yh = acc + b[j];
    yhat[t * NY + j] = yh;
    ep[t * NY + j] = Y[t * NY + j] - yh;
}

// ---------------- kernel 2: one DRO solve per block ----------------
// Structure: ONE barrier per iteration.
//  - phase A (per-thread row dot, ep in regs, z from wave-PRIVATE LDS copy)
//  - w_s is wave-private (producer lanes == consumer wave) -> no barrier A->B
//  - phase B per-wave partial gz (ep cols in regs, w broadcast from own LDS)
//  - S1/S2 DPP reduction overlaps phase B
//  - barrier
//  - ALL waves redundantly: scalar update + full gz + Michelot projection,
//    each writes new z to its own z_s[wid] (wave-local, lgkmcnt-ordered)
//  - gzp/red double-buffered by iteration parity (write@k+2 vs read@k are
//    separated by barrier@k+1)
__global__ __launch_bounds__(256, 1)
void dro_kernel(const float* __restrict__ ep_g, const float* __restrict__ yhat_g,
                float* __restrict__ z_out,
                const float* __restrict__ d_delta, const float* __restrict__ d_gamma) {
    __shared__ float z_s[4][NY];                 // per-wave private z copy
    __shared__ float w_s[4][64];                 // per-wave private w
    __shared__ float gzp[2][4][NY];              // cross-wave partials, dbuf
    __shared__ __align__(16) float red[2][8];    // cross-wave {S1,S2}, dbuf

    const int tid  = threadIdx.x;
    const int lane = tid & 63;
    const int wid  = tid >> 6;
    const int blk  = blockIdx.x;

    // row layout: thread tid holds ep[tid][0..127]
    float4 rA[32];
    {
        const float4* eg4 = (const float4*)ep_g + tid * 32;
#pragma unroll
        for (int q = 0; q < 32; ++q) rA[q] = eg4[q];
    }

    // col layout: lane holds ep[tbase+tt][j0..j0+1]
    const int j0    = lane << 1;
    const int tbase = wid << 6;
    float2 rB[64];
#pragma unroll
    for (int tt = 0; tt < 64; ++tt)
        rB[tt] = *(const float2*)(ep_g + (tbase + tt) * NY + j0);

    // per-lane y_hat pair (wave-redundant)
    const float yh0 = yhat_g[blk * NY + j0];
    const float yh1 = yhat_g[blk * NY + j0 + 1];

    // init z: registers + own wave's LDS copy (wave-local ordering only)
    float z0 = 1.0f / 128.0f, z1 = 1.0f / 128.0f;
    *(float2*)&z_s[wid][j0] = make_float2(z0, z1);

    const float delta = d_delta[0];
    const float gamma = d_gamma[0];
    float c = 0.f, eta = 0.f, lam = 0.1f;
    int buf = 0;

    for (int k = 0; k < NITER; ++k) {
        const float lr = 0.05f / sqrtf(1.0f + (float)k);

        // ---- phase A: r_t = ep[t,:].z - c (z from own wave's LDS copy) ----
        const float4* z4p = (const float4*)z_s[wid];
        float4 a4 = make_float4(0.f, 0.f, 0.f, 0.f);
#pragma unroll
        for (int q = 0; q < 32; ++q) {
            const float4 e4 = rA[q];
            const float4 z4 = z4p[q];
            a4.x = fmaf(e4.x, z4.x, a4.x);
            a4.y = fmaf(e4.y, z4.y, a4.y);
            a4.z = fmaf(e4.z, z4.z, a4.z);
            a4.w = fmaf(e4.w, z4.w, a4.w);
        }
        const float r  = (a4.x + a4.y) + (a4.z + a4.w) - c;
        const float q2 = r * r - eta;
        const float aa = -lam;
        const float st = (q2 > aa) ? 1.0f : ((q2 == aa) ? 0.5f : 0.0f);
        const float wv = st * r;
        w_s[wid][lane] = wv;            // wave-private; lgkmcnt orders vs reads below

        // ---- S1/S2 reduction (overlaps phase B scheduling) ----
        float s1 = st, s2 = wv;
        wave_sum2(s1, s2);
        if (lane == 0) { red[buf][wid * 2] = s1; red[buf][wid * 2 + 1] = s2; }

        // ---- phase B: per-wave partial gz over own 64 rows ----
        float p0 = 0.f, p1 = 0.f;
#pragma unroll
        for (int g = 0; g < 16; ++g) {
            const float4 w4 = *(const float4*)&w_s[wid][g << 2];
            const float2 e0 = rB[(g << 2) + 0];
            const float2 e1 = rB[(g << 2) + 1];
            const float2 e2 = rB[(g << 2) + 2];
            const float2 e3 = rB[(g << 2) + 3];
            p0 = fmaf(w4.x, e0.x, p0); p1 = fmaf(w4.x, e0.y, p1);
            p0 = fmaf(w4.y, e1.x, p0); p1 = fmaf(w4.y, e1.y, p1);
            p0 = fmaf(w4.z, e2.x, p0); p1 = fmaf(w4.z, e2.y, p1);
            p0 = fmaf(w4.w, e3.x, p0); p1 = fmaf(w4.w, e3.y, p1);
        }
        *(float2*)&gzp[buf][wid][j0] = make_float2(p0, p1);

        __syncthreads();   // the ONE barrier: gzp[buf] + red[buf] visible

        // ---- all waves redundantly: scalar updates + z step + projection ----
        const float4 rd0 = *(const float4*)&red[buf][0];
        const float4 rd1 = *(const float4*)&red[buf][4];
        const float S1 = (rd0.x + rd0.z) + (rd1.x + rd1.z);
        const float S2 = (rd0.y + rd0.w) + (rd1.y + rd1.w);
        c   -= lr * (-(2.0f / 256.0f) * S2);
        eta -= lr * (1.0f - S1 * (1.0f / 256.0f));
        lam  = fmaxf(lam - lr * (delta - 1.0f + S1 * (1.0f / 256.0f)), 0.0f);

        const float2 q0 = *(const float2*)&gzp[buf][0][j0];
        const float2 q1 = *(const float2*)&gzp[buf][1][j0];
        const float2 q2v = *(const float2*)&gzp[buf][2][j0];
        const float2 q3 = *(const float2*)&gzp[buf][3][j0];
        const float g0 = (q0.x + q1.x) + (q2v.x + q3.x);
        const float g1 = (q0.y + q1.y) + (q2v.y + q3.y);
        const float v0 = z0 - lr * ((2.0f / 256.0f) * g0 - gamma * yh0);
        const float v1 = z1 - lr * ((2.0f / 256.0f) * g1 - gamma * yh1);

        // Michelot active-set projection (per-wave redundant, DPP reductions)
        float act0 = 1.f, act1 = 1.f;
        float prev = 1e30f;
        float theta = 0.f;
        for (int m = 0; m < 64; ++m) {
            float s  = act0 * v0 + act1 * v1;
            float cc = act0 + act1;
            wave_sum2(s, cc);
            theta = (s - 1.0f) / cc;
            if (cc == prev) break;     // uniform branch
            prev = cc;
            act0 = (v0 > theta) ? act0 : 0.f;
            act1 = (v1 > theta) ? act1 : 0.f;
        }
        z0 = fmaxf(v0 - theta, 0.f);
        z1 = fmaxf(v1 - theta, 0.f);
        *(float2*)&z_s[wid][j0] = make_float2(z0, z1);   // own copy, wave-local

        buf ^= 1;
    }

    if (wid == 0) *(float2*)&z_out[blk * NY + j0] = make_float2(z0, z1);
}

extern "C" void kernel_launch(void* const* d_in, const int* in_sizes, int n_in,
                              void* d_out, int out_size, void* d_ws, size_t ws_size,
                              hipStream_t stream) {
    const float* X       = (const float*)d_in[0];   // 256*64
    const float* Y       = (const float*)d_in[1];   // 256*128
    const float* W       = (const float*)d_in[2];   // 128*64
    const float* b       = (const float*)d_in[3];   // 128
    const float* d_delta = (const float*)d_in[4];   // 1
    const float* d_gamma = (const float*)d_in[5];   // 1

    float* z_out    = (float*)d_out;                // Z_star: 256*128
    float* yhat_out = z_out + T_OBS * NY;           // Y_hat:  256*128
    float* ep_ws    = (float*)d_ws;                 // 256*128 scratch

    pred_kernel<<<T_OBS, 128, 0, stream>>>(X, Y, W, b, yhat_out, ep_ws);
    dro_kernel<<<T_OBS, 256, 0, stream>>>(ep_ws, yhat_out, z_out, d_delta, d_gamma);
}

// Round 4
// 237.993 us; speedup vs baseline: 2.6159x; 1.5610x over previous
//
#include <hip/hip_runtime.h>
#include <math.h>

#define T_OBS 256
#define NY 128
#define NITER 150

// ---- gfx9/CDNA DPP wave64 reduction: row_shr 1,2,4,8 + bcast15 + bcast31 ----
#define DPP_ROW_SHR1 0x111
#define DPP_ROW_SHR2 0x112
#define DPP_ROW_SHR4 0x114
#define DPP_ROW_SHR8 0x118
#define DPP_BCAST15  0x142
#define DPP_BCAST31  0x143

#define DPP_ADD_F32(x, ctrl) \
    (x) += __int_as_float(__builtin_amdgcn_update_dpp(0, __float_as_int(x), (ctrl), 0xf, 0xf, true))

// Interleaved dual wave-sum; returns uniform totals in a,b.
__device__ __forceinline__ void wave_sum2(float& a, float& b) {
    DPP_ADD_F32(a, DPP_ROW_SHR1); DPP_ADD_F32(b, DPP_ROW_SHR1);
    DPP_ADD_F32(a, DPP_ROW_SHR2); DPP_ADD_F32(b, DPP_ROW_SHR2);
    DPP_ADD_F32(a, DPP_ROW_SHR4); DPP_ADD_F32(b, DPP_ROW_SHR4);
    DPP_ADD_F32(a, DPP_ROW_SHR8); DPP_ADD_F32(b, DPP_ROW_SHR8);
    DPP_ADD_F32(a, DPP_BCAST15);  DPP_ADD_F32(b, DPP_BCAST15);
    DPP_ADD_F32(a, DPP_BCAST31);  DPP_ADD_F32(b, DPP_BCAST31);
    a = __int_as_float(__builtin_amdgcn_readlane(__float_as_int(a), 63));
    b = __int_as_float(__builtin_amdgcn_readlane(__float_as_int(b), 63));
}

__device__ __forceinline__ float rl(float x, int l) {
    return __int_as_float(__builtin_amdgcn_readlane(__float_as_int(x), l));
}

// ---------------- kernel 1: Y_hat = X @ W^T + b ; ep = Y - Y_hat ----------------
__global__ __launch_bounds__(128)
void pred_kernel(const float* __restrict__ X, const float* __restrict__ Y,
                 const float* __restrict__ W, const float* __restrict__ b,
                 float* __restrict__ yhat, float* __restrict__ ep) {
    __shared__ float xrow[64];
    const int t = blockIdx.x;
    const int j = threadIdx.x;
    if (j < 64) xrow[j] = X[t * 64 + j];
    __syncthreads();
    const float* wr = W + j * 64;
    float acc = 0.f;
#pragma unroll
    for (int x = 0; x < 64; ++x) acc = fmaf(xrow[x], wr[x], acc);
    const float yh = acc + b[j];
    yhat[t * NY + j] = yh;
    ep[t * NY + j] = Y[t * NY + j] - yh;
}

// ---------------- kernel 2: one DRO solve per block ----------------
// Per-iteration LDS = ONLY the cross-wave gzp/red exchange (dbuf, 1 barrier).
// All broadcasts (z in phase A, w in phase B) are v_readlane register
// broadcasts on the per-SIMD VALU pipe instead of the shared per-CU LDS pipe.
__global__ __launch_bounds__(256, 1)
void dro_kernel(const float* __restrict__ ep_g, const float* __restrict__ yhat_g,
                float* __restrict__ z_out,
                const float* __restrict__ d_delta, const float* __restrict__ d_gamma) {
    __shared__ float gzp[2][4][NY];              // cross-wave partials, dbuf
    __shared__ __align__(16) float red[2][8];    // cross-wave {S1,S2}, dbuf

    const int tid  = threadIdx.x;
    const int lane = tid & 63;
    const int wid  = tid >> 6;
    const int blk  = blockIdx.x;

    // row layout: thread tid holds ep[tid][0..127] (128 VGPRs)
    float4 rA[32];
    {
        const float4* eg4 = (const float4*)ep_g + tid * 32;
#pragma unroll
        for (int q = 0; q < 32; ++q) rA[q] = eg4[q];
    }

    // col layout: lane holds ep[tbase+tt][j0..j0+1] (128 VGPRs)
    const int j0    = lane << 1;
    const int tbase = wid << 6;
    float2 rB[64];
#pragma unroll
    for (int tt = 0; tt < 64; ++tt)
        rB[tt] = *(const float2*)(ep_g + (tbase + tt) * NY + j0);

    const float yh0 = yhat_g[blk * NY + j0];
    const float yh1 = yhat_g[blk * NY + j0 + 1];

    // z pair in registers (each wave holds a full redundant copy across lanes)
    float z0 = 1.0f / 128.0f, z1 = 1.0f / 128.0f;
    // Michelot warm-start support indicators (carried across iterations)
    float act0 = 1.f, act1 = 1.f;

    const float delta = d_delta[0];
    const float gamma = d_gamma[0];
    float c = 0.f, eta = 0.f, lam = 0.1f;
    int buf = 0;

    for (int k = 0; k < NITER; ++k) {
        const float lr = 0.05f * __builtin_amdgcn_rsqf(1.0f + (float)k);

        // ---- phase A: r_t = ep[t,:].z - c ; z broadcast via readlane ----
        float a0 = 0.f, a1 = 0.f, a2 = 0.f, a3 = 0.f;
#pragma unroll
        for (int q = 0; q < 32; ++q) {
            const float4 e = rA[q];
            const float za = rl(z0, 2 * q);
            const float zb = rl(z1, 2 * q);
            const float zc = rl(z0, 2 * q + 1);
            const float zd = rl(z1, 2 * q + 1);
            a0 = fmaf(e.x, za, a0);
            a1 = fmaf(e.y, zb, a1);
            a2 = fmaf(e.z, zc, a2);
            a3 = fmaf(e.w, zd, a3);
        }
        const float r  = (a0 + a1) + (a2 + a3) - c;
        const float q2 = r * r - eta;
        const float aa = -lam;
        const float st = (q2 > aa) ? 1.0f : ((q2 == aa) ? 0.5f : 0.0f);
        const float wv = st * r;

        // ---- S1/S2 reduction (independent of phase B; scheduler interleaves) ----
        float s1 = st, s2 = wv;
        wave_sum2(s1, s2);
        if (lane == 0) { red[buf][wid * 2] = s1; red[buf][wid * 2 + 1] = s2; }

        // ---- phase B: per-wave partial gz over own 64 rows; w via readlane ----
        float p0 = 0.f, p1 = 0.f, p2 = 0.f, p3 = 0.f;
#pragma unroll
        for (int tt = 0; tt < 64; tt += 2) {
            const float wa = rl(wv, tt);
            const float wb = rl(wv, tt + 1);
            const float2 ea = rB[tt];
            const float2 eb = rB[tt + 1];
            p0 = fmaf(wa, ea.x, p0);
            p1 = fmaf(wa, ea.y, p1);
            p2 = fmaf(wb, eb.x, p2);
            p3 = fmaf(wb, eb.y, p3);
        }
        *(float2*)&gzp[buf][wid][j0] = make_float2(p0 + p2, p1 + p3);

        __syncthreads();   // the ONE barrier: gzp[buf] + red[buf] visible

        // ---- all waves redundantly: scalar updates + z step + projection ----
        const float4 rd0 = *(const float4*)&red[buf][0];
        const float4 rd1 = *(const float4*)&red[buf][4];
        const float S1 = (rd0.x + rd0.z) + (rd1.x + rd1.z);
        const float S2 = (rd0.y + rd0.w) + (rd1.y + rd1.w);
        c   -= lr * (-(2.0f / 256.0f) * S2);
        eta -= lr * (1.0f - S1 * (1.0f / 256.0f));
        lam  = fmaxf(lam - lr * (delta - 1.0f + S1 * (1.0f / 256.0f)), 0.0f);

        const float2 g0v = *(const float2*)&gzp[buf][0][j0];
        const float2 g1v = *(const float2*)&gzp[buf][1][j0];
        const float2 g2v = *(const float2*)&gzp[buf][2][j0];
        const float2 g3v = *(const float2*)&gzp[buf][3][j0];
        const float g0 = (g0v.x + g1v.x) + (g2v.x + g3v.x);
        const float g1 = (g0v.y + g1v.y) + (g2v.y + g3v.y);
        const float v0 = z0 - lr * ((2.0f / 256.0f) * g0 - gamma * yh0);
        const float v1 = z1 - lr * ((2.0f / 256.0f) * g1 - gamma * yh1);

        // ---- Michelot projection: warm start + ballot fixed-point test.
        // Fixed point + no external violator == exact KKT theta.
        float theta = 0.f;
        for (int attempt = 0; attempt < 2; ++attempt) {
            for (int m = 0; m < 128; ++m) {
                float s  = act0 * v0 + act1 * v1;
                float cc = act0 + act1;
                wave_sum2(s, cc);
                theta = (s - 1.0f) * __builtin_amdgcn_rcpf(cc);
                const float n0 = (v0 > theta) ? act0 : 0.f;
                const float n1 = (v1 > theta) ? act1 : 0.f;
                const bool changed = (n0 != act0) || (n1 != act1);
                act0 = n0; act1 = n1;
                if (!__any(changed)) break;   // uniform
            }
            const bool viol = ((act0 == 0.f) && (v0 > theta)) ||
                              ((act1 == 0.f) && (v1 > theta));
            if (!__any(viol)) break;          // exact
            act0 = 1.f; act1 = 1.f;           // rare: support grew, restart full
        }
        z0 = fmaxf(v0 - theta, 0.f);
        z1 = fmaxf(v1 - theta, 0.f);

        buf ^= 1;
    }

    if (wid == 0) *(float2*)&z_out[blk * NY + j0] = make_float2(z0, z1);
}

extern "C" void kernel_launch(void* const* d_in, const int* in_sizes, int n_in,
                              void* d_out, int out_size, void* d_ws, size_t ws_size,
                              hipStream_t stream) {
    const float* X       = (const float*)d_in[0];   // 256*64
    const float* Y       = (const float*)d_in[1];   // 256*128
    const float* W       = (const float*)d_in[2];   // 128*64
    const float* b       = (const float*)d_in[3];   // 128
    const float* d_delta = (const float*)d_in[4];   // 1
    const float* d_gamma = (const float*)d_in[5];   // 1

    float* z_out    = (float*)d_out;                // Z_star: 256*128
    float* yhat_out = z_out + T_OBS * NY;           // Y_hat:  256*128
    float* ep_ws    = (float*)d_ws;                 // 256*128 scratch

    pred_kernel<<<T_OBS, 128, 0, stream>>>(X, Y, W, b, yhat_out, ep_ws);
    dro_kernel<<<T_OBS, 256, 0, stream>>>(ep_ws, yhat_out, z_out, d_delta, d_gamma);
}